// Round 2
// baseline (1922.380 us; speedup 1.0000x reference)
//
#include <hip/hip_runtime.h>

#define NN 8192
#define DD 512
#define KTOP 16

typedef __attribute__((ext_vector_type(8))) short short8;
typedef __attribute__((ext_vector_type(4))) float f32x4;

__device__ __forceinline__ unsigned short f2bf(float f) {
  unsigned int b = __float_as_uint(f);
  b += 0x7FFFu + ((b >> 16) & 1u);
  return (unsigned short)(b >> 16);
}

// ---------------- Kernel A: cast x -> bf16 (ws) and copy x -> out ----------
__global__ void knn_cast_copy(const float* __restrict__ x,
                              unsigned short* __restrict__ xb,
                              float* __restrict__ xout) {
  int i = blockIdx.x * blockDim.x + threadIdx.x;
  const int total = NN * DD / 4;  // float4 count
  for (; i < total; i += gridDim.x * blockDim.x) {
    const float4 v = ((const float4*)x)[i];
    ((float4*)xout)[i] = v;
    ushort4 o;
    o.x = f2bf(v.x); o.y = f2bf(v.y); o.z = f2bf(v.z); o.w = f2bf(v.w);
    ((ushort4*)xb)[i] = o;
  }
}

// ---------------- Kernel B: bf16 MFMA GEMM tile + per-tile top-16 ----------
// grid (64 col-tiles, 64 row-tiles), 256 threads. Tile 128x128, BK=64.
// LDS A/B tiles use padded rows: 64 bf16 data + 8 pad = 72 shorts (144 B)
// -> frag ds_read_b128 is 2-way bank aliased (free).
// Per-tile per-row top-16 candidates are stashed INSIDE the adj output row:
//   adj[row][ct*16 + k]        = candidate value (float)
//   adj[row][1024 + ct*16 + k] = candidate index (int bitcast)
// Kernel C reads them back before zeroing the row.
#define AB_ROWB 144
#define B_OFF (128 * AB_ROWB)  // 18432

__global__ __launch_bounds__(256, 2)
void knn_gemm_topk(const unsigned short* __restrict__ xb,
                   float* __restrict__ adj) {
  __shared__ char smem[128 * 128 * 4];  // 64 KiB (fp32 tile reuses stage area)
  const int t = threadIdx.x;
  const int lane = t & 63;
  const int wid = t >> 6;
  const int wr = wid >> 1;
  const int wc = wid & 1;
  const int ct = blockIdx.x;
  const int rt = blockIdx.y;

  const int r0 = t >> 3;      // staging row base (0..31)
  const int p0 = t & 7;       // 16B granule within row

  f32x4 zero4 = {0.f, 0.f, 0.f, 0.f};
  f32x4 acc[4][4];
#pragma unroll
  for (int i = 0; i < 4; ++i)
#pragma unroll
    for (int j = 0; j < 4; ++j) acc[i][j] = zero4;

  const unsigned short* abase = xb + (size_t)(rt * 128) * DD;
  const unsigned short* bbase = xb + (size_t)(ct * 128) * DD;

  short8 ra0, ra1, ra2, ra3, rb0, rb1, rb2, rb3;

  auto loadk = [&](int kt) {
    const unsigned short* ap = abase + (size_t)r0 * DD + kt * 64 + p0 * 8;
    ra0 = *(const short8*)(ap);
    ra1 = *(const short8*)(ap + 32 * DD);
    ra2 = *(const short8*)(ap + 64 * DD);
    ra3 = *(const short8*)(ap + 96 * DD);
    const unsigned short* bp = bbase + (size_t)r0 * DD + kt * 64 + p0 * 8;
    rb0 = *(const short8*)(bp);
    rb1 = *(const short8*)(bp + 32 * DD);
    rb2 = *(const short8*)(bp + 64 * DD);
    rb3 = *(const short8*)(bp + 96 * DD);
  };

  auto store_lds = [&]() {
    char* al = smem + r0 * AB_ROWB + p0 * 16;
    *(short8*)(al)                 = ra0;
    *(short8*)(al + 32 * AB_ROWB)  = ra1;
    *(short8*)(al + 64 * AB_ROWB)  = ra2;
    *(short8*)(al + 96 * AB_ROWB)  = ra3;
    char* bl = smem + B_OFF + r0 * AB_ROWB + p0 * 16;
    *(short8*)(bl)                 = rb0;
    *(short8*)(bl + 32 * AB_ROWB)  = rb1;
    *(short8*)(bl + 64 * AB_ROWB)  = rb2;
    *(short8*)(bl + 96 * AB_ROWB)  = rb3;
  };

  const int rA = (wr * 64 + (lane & 15)) * AB_ROWB + ((lane >> 4) << 4);
  const int rB = B_OFF + (wc * 64 + (lane & 15)) * AB_ROWB + ((lane >> 4) << 4);

  auto compute = [&]() {
#pragma unroll
    for (int kk = 0; kk < 2; ++kk) {
      short8 af[4], bf[4];
#pragma unroll
      for (int mi = 0; mi < 4; ++mi)
        af[mi] = *(const short8*)(smem + rA + mi * 16 * AB_ROWB + kk * 64);
#pragma unroll
      for (int ni = 0; ni < 4; ++ni)
        bf[ni] = *(const short8*)(smem + rB + ni * 16 * AB_ROWB + kk * 64);
#pragma unroll
      for (int mi = 0; mi < 4; ++mi)
#pragma unroll
        for (int ni = 0; ni < 4; ++ni)
          acc[mi][ni] = __builtin_amdgcn_mfma_f32_16x16x32_bf16(
              af[mi], bf[ni], acc[mi][ni], 0, 0, 0);
    }
  };

  loadk(0);
  for (int kt = 0; kt < 8; ++kt) {
    __syncthreads();        // previous compute done reading LDS
    store_lds();
    __syncthreads();        // tile visible
    if (kt < 7) loadk(kt + 1);  // prefetch next K-slice under compute
    compute();
  }

  // ---- write sim tile to LDS (fp32, reuse stage memory) ----
  __syncthreads();
  float* tile = (float*)smem;
#pragma unroll
  for (int mi = 0; mi < 4; ++mi)
#pragma unroll
    for (int ni = 0; ni < 4; ++ni)
#pragma unroll
      for (int r = 0; r < 4; ++r) {
        int row = wr * 64 + mi * 16 + ((lane >> 4) << 2) + r;
        int col = wc * 64 + ni * 16 + (lane & 15);
        tile[row * 128 + col] = acc[mi][ni][r];
      }
  __syncthreads();

  // ---- per-row top-16 within the 128-col tile (one thread per row) ----
  if (t < 128) {
    float v[16];
    int ix[16];
#pragma unroll
    for (int i = 0; i < 16; ++i) { v[i] = -__builtin_inff(); ix[i] = 0; }
    const float* trow = tile + t * 128;
    const int cbase = ct * 128;
    for (int c = 0; c < 128; ++c) {
      int cc = (c + t) & 127;  // rotated scan: conflict-free LDS reads
      float val = trow[cc];
      if (val > v[15]) {
        float cv = val;
        int cidx = cbase + cc;
#pragma unroll
        for (int i = 0; i < 16; ++i) {
          if (cv > v[i]) {
            float tv = v[i]; v[i] = cv; cv = tv;
            int ti = ix[i]; ix[i] = cidx; cidx = ti;
          }
        }
      }
    }
    const size_t rowbase = (size_t)(rt * 128 + t) * NN;
    float* vout = adj + rowbase + ct * 16;
    int* iout = (int*)(adj + rowbase + 1024) + ct * 16;
#pragma unroll
    for (int k = 0; k < 16; ++k) { vout[k] = v[k]; iout[k] = ix[k]; }
  }
}

// ---------------- Kernel C: merge + zero row + fp64 rescore + scatter ------
// one wave per row; 4 rows per 256-thread block.
__global__ __launch_bounds__(256)
void knn_final(const float* __restrict__ x, float* __restrict__ adj) {
  const int t = threadIdx.x;
  const int lane = t & 63;
  const int w = t >> 6;
  const int r = blockIdx.x * 4 + w;

  float* rowp = adj + (size_t)r * NN;
  const float* candv = rowp;                     // [64][16] values
  const int* candi = (const int*)(rowp + 1024);  // [64][16] indices

  // phase 1: merge 64 sorted 16-lists -> approx top-32 (lane l owns list l)
  float hv = candv[lane * 16];
  int hi = candi[lane * 16];
  int p = 0;
  int seli = 0;
#pragma unroll 1
  for (int i = 0; i < 32; ++i) {
    float m = hv;
#pragma unroll
    for (int o = 1; o < 64; o <<= 1) m = fmaxf(m, __shfl_xor(m, o));
    unsigned long long msk = __ballot(hv == m);
    int wl = (int)__ffsll(msk) - 1;
    int si = __shfl(hi, wl);
    if (lane == i) seli = si;
    if (lane == wl) {
      ++p;
      hv = (p < 16) ? candv[lane * 16 + p] : -__builtin_inff();
      hi = (p < 16) ? candi[lane * 16 + p] : 0;
    }
  }

  // phase 0 (after reads): zero this row of adj
  {
    float4 z; z.x = z.y = z.z = z.w = 0.f;
    float4* rp = (float4*)rowp;
#pragma unroll
    for (int it = 0; it < 32; ++it) rp[it * 64 + lane] = z;
  }
  __syncthreads();  // drains vmcnt: zero-stores ordered before scatter stores

  // phase 2: fp64 rescore of the 32 candidates (exact selection values)
  float xr[8];
  {
    const float4* xp = (const float4*)(x + (size_t)r * DD + lane * 8);
    float4 a = xp[0], b = xp[1];
    xr[0] = a.x; xr[1] = a.y; xr[2] = a.z; xr[3] = a.w;
    xr[4] = b.x; xr[5] = b.y; xr[6] = b.z; xr[7] = b.w;
  }
  double dval = -1.0e300;
#pragma unroll 1
  for (int i = 0; i < 32; ++i) {
    int ci = __shfl(seli, i);
    const float4* cp = (const float4*)(x + (size_t)ci * DD + lane * 8);
    float4 a = cp[0], b = cp[1];
    double s = (double)xr[0] * a.x + (double)xr[1] * a.y +
               (double)xr[2] * a.z + (double)xr[3] * a.w +
               (double)xr[4] * b.x + (double)xr[5] * b.y +
               (double)xr[6] * b.z + (double)xr[7] * b.w;
#pragma unroll
    for (int o = 1; o < 64; o <<= 1) s += __shfl_xor(s, o);
    if (lane == i) dval = s;
  }

  // phase 3: exact top-16 of 32, scatter into adj row
#pragma unroll 1
  for (int k = 0; k < KTOP; ++k) {
    double m = dval;
#pragma unroll
    for (int o = 1; o < 64; o <<= 1) m = fmax(m, __shfl_xor(m, o));
    unsigned long long msk = __ballot(dval == m);
    int wl = (int)__ffsll(msk) - 1;
    if (lane == wl) {
      rowp[seli] = (float)dval;
      dval = -1.0e300;
    }
  }
}

extern "C" void kernel_launch(void* const* d_in, const int* in_sizes, int n_in,
                              void* d_out, int out_size, void* d_ws, size_t ws_size,
                              hipStream_t stream) {
  const float* x = (const float*)d_in[0];
  float* out = (float*)d_out;
  float* adj = out + (size_t)NN * DD;  // adj after the x copy

  unsigned short* xb = (unsigned short*)d_ws;  // 8 MiB bf16 copy of x

  knn_cast_copy<<<2048, 256, 0, stream>>>(x, xb, out);
  knn_gemm_topk<<<dim3(64, 64), 256, 0, stream>>>(xb, adj);
  knn_final<<<NN / 4, 256, 0, stream>>>(x, adj);
}

// Round 3
// 504.564 us; speedup vs baseline: 3.8100x; 3.8100x over previous
//
#include <hip/hip_runtime.h>

#define NN 8192
#define DD 512
#define KTOP 16

typedef __attribute__((ext_vector_type(8))) short short8;
typedef __attribute__((ext_vector_type(4))) float f32x4;

__device__ __forceinline__ unsigned short f2bf(float f) {
  unsigned int b = __float_as_uint(f);
  b += 0x7FFFu + ((b >> 16) & 1u);
  return (unsigned short)(b >> 16);
}

// ---------------- Kernel A: cast x -> bf16 (ws) and copy x -> out ----------
__global__ void knn_cast_copy(const float* __restrict__ x,
                              unsigned short* __restrict__ xb,
                              float* __restrict__ xout) {
  int i = blockIdx.x * blockDim.x + threadIdx.x;
  const int total = NN * DD / 4;
  for (; i < total; i += gridDim.x * blockDim.x) {
    const float4 v = ((const float4*)x)[i];
    ((float4*)xout)[i] = v;
    ushort4 o;
    o.x = f2bf(v.x); o.y = f2bf(v.y); o.z = f2bf(v.z); o.w = f2bf(v.w);
    ((ushort4*)xb)[i] = o;
  }
}

// ---------------- Kernel B: pure bf16 MFMA GEMM, fp32 C -> adj -------------
// 128x128 tile, BK=64, 4 waves. Padded LDS rows (144 B) for low-conflict
// ds_read_b128. Writes the full sim tile to adj (coalesced per 16-lane row
// segments). No top-k here.
#define AB_ROWB 144
#define B_OFF (128 * AB_ROWB)  // 18432 B

__global__ __launch_bounds__(256, 4)
void knn_gemm(const unsigned short* __restrict__ xb, float* __restrict__ adj) {
  __shared__ char smem[2 * B_OFF];  // 36 KiB
  const int t = threadIdx.x;
  const int lane = t & 63;
  const int wid = t >> 6;
  const int wr = wid >> 1;
  const int wc = wid & 1;

  // bijective XCD swizzle: 4096 blocks, 8 XCDs -> contiguous rt chunks/XCD
  const int bid = blockIdx.y * 64 + blockIdx.x;
  const int swz = (bid & 7) * 512 + (bid >> 3);
  const int ct = swz & 63;
  const int rt = swz >> 6;

  const int r0 = t >> 3;  // staging row (0..31)
  const int p0 = t & 7;   // 16B granule in 64-col row

  f32x4 zero4 = {0.f, 0.f, 0.f, 0.f};
  f32x4 acc[4][4];
#pragma unroll
  for (int i = 0; i < 4; ++i)
#pragma unroll
    for (int j = 0; j < 4; ++j) acc[i][j] = zero4;

  const unsigned short* abase = xb + (size_t)(rt * 128) * DD;
  const unsigned short* bbase = xb + (size_t)(ct * 128) * DD;

  short8 ra0, ra1, ra2, ra3, rb0, rb1, rb2, rb3;

  auto loadk = [&](int kt) {
    const unsigned short* ap = abase + (size_t)r0 * DD + kt * 64 + p0 * 8;
    ra0 = *(const short8*)(ap);
    ra1 = *(const short8*)(ap + 32 * DD);
    ra2 = *(const short8*)(ap + 64 * DD);
    ra3 = *(const short8*)(ap + 96 * DD);
    const unsigned short* bp = bbase + (size_t)r0 * DD + kt * 64 + p0 * 8;
    rb0 = *(const short8*)(bp);
    rb1 = *(const short8*)(bp + 32 * DD);
    rb2 = *(const short8*)(bp + 64 * DD);
    rb3 = *(const short8*)(bp + 96 * DD);
  };

  auto store_lds = [&]() {
    char* al = smem + r0 * AB_ROWB + p0 * 16;
    *(short8*)(al)                = ra0;
    *(short8*)(al + 32 * AB_ROWB) = ra1;
    *(short8*)(al + 64 * AB_ROWB) = ra2;
    *(short8*)(al + 96 * AB_ROWB) = ra3;
    char* bl = smem + B_OFF + r0 * AB_ROWB + p0 * 16;
    *(short8*)(bl)                = rb0;
    *(short8*)(bl + 32 * AB_ROWB) = rb1;
    *(short8*)(bl + 64 * AB_ROWB) = rb2;
    *(short8*)(bl + 96 * AB_ROWB) = rb3;
  };

  const int rA = (wr * 64 + (lane & 15)) * AB_ROWB + ((lane >> 4) << 4);
  const int rB = B_OFF + (wc * 64 + (lane & 15)) * AB_ROWB + ((lane >> 4) << 4);

  auto compute = [&]() {
#pragma unroll
    for (int kk = 0; kk < 2; ++kk) {
      short8 af[4], bf[4];
#pragma unroll
      for (int mi = 0; mi < 4; ++mi)
        af[mi] = *(const short8*)(smem + rA + mi * 16 * AB_ROWB + kk * 64);
#pragma unroll
      for (int ni = 0; ni < 4; ++ni)
        bf[ni] = *(const short8*)(smem + rB + ni * 16 * AB_ROWB + kk * 64);
#pragma unroll
      for (int mi = 0; mi < 4; ++mi)
#pragma unroll
        for (int ni = 0; ni < 4; ++ni)
          acc[mi][ni] = __builtin_amdgcn_mfma_f32_16x16x32_bf16(
              af[mi], bf[ni], acc[mi][ni], 0, 0, 0);
    }
  };

  loadk(0);
  for (int kt = 0; kt < 8; ++kt) {
    __syncthreads();
    store_lds();
    __syncthreads();
    if (kt < 7) loadk(kt + 1);
    compute();
  }

  // epilogue: direct fp32 tile write (C/D layout: col=lane&15, row=(lane>>4)*4+r)
  float* cbase = adj + (size_t)(rt * 128) * NN + ct * 128;
#pragma unroll
  for (int mi = 0; mi < 4; ++mi)
#pragma unroll
    for (int r = 0; r < 4; ++r) {
      int row = wr * 64 + mi * 16 + ((lane >> 4) << 2) + r;
      float* rp = cbase + (size_t)row * NN + wc * 64 + (lane & 15);
#pragma unroll
      for (int ni = 0; ni < 4; ++ni) rp[ni * 16] = acc[mi][ni][r];
    }
}

// ---------------- Kernel C: per-row threshold select + fp64 rescore --------
// One 256-thread block per row. Row (8192 f32) -> 32 regs/thread.
// Bisection for tau with count(>=tau) in [24,64]; compact indices; fp64
// rescore; exact top-16; zero row; scatter.
__global__ __launch_bounds__(256)
void knn_rowtopk(const float* __restrict__ x, float* __restrict__ adj) {
  const int t = threadIdx.x;
  const int lane = t & 63;
  const int w = t >> 6;
  const int r = blockIdx.x;
  float* rowp = adj + (size_t)r * NN;

  __shared__ float red[8];
  __shared__ int redi[4];
  __shared__ int nlist;
  __shared__ int list[64];
  __shared__ double dv[64];
  __shared__ double fv16[KTOP];
  __shared__ int fidx16[KTOP];

  // 1. row -> regs (strided float4, coalesced)
  float v[32];
  {
    const float4* rp4 = (const float4*)rowp;
#pragma unroll
    for (int i = 0; i < 8; ++i) {
      float4 q = rp4[t + i * 256];
      v[i * 4 + 0] = q.x; v[i * 4 + 1] = q.y;
      v[i * 4 + 2] = q.z; v[i * 4 + 3] = q.w;
    }
  }

  // 2. block max/min
  float mx = v[0], mn = v[0];
#pragma unroll
  for (int i = 1; i < 32; ++i) { mx = fmaxf(mx, v[i]); mn = fminf(mn, v[i]); }
#pragma unroll
  for (int o = 1; o < 64; o <<= 1) {
    mx = fmaxf(mx, __shfl_xor(mx, o));
    mn = fminf(mn, __shfl_xor(mn, o));
  }
  if (lane == 0) { red[w] = mx; red[4 + w] = mn; }
  __syncthreads();
  const float M = fmaxf(fmaxf(red[0], red[1]), fmaxf(red[2], red[3]));
  const float m = fminf(fminf(red[4], red[5]), fminf(red[6], red[7]));
  __syncthreads();

  // 3. bisect threshold
  float a = m - 1.0f, b = M + 1.0f;
  float tau = 0.5f * (a + b);
  bool found = false;
  for (int it = 0; it < 40 && !found; ++it) {
    tau = 0.5f * (a + b);
    int c = 0;
#pragma unroll
    for (int i = 0; i < 32; ++i) c += (v[i] >= tau) ? 1 : 0;
#pragma unroll
    for (int o = 1; o < 64; o <<= 1) c += __shfl_xor(c, o);
    if (lane == 0) redi[w] = c;
    __syncthreads();
    int cnt = redi[0] + redi[1] + redi[2] + redi[3];
    __syncthreads();
    if (cnt > 64) a = tau;
    else if (cnt < 24) b = tau;
    else found = true;
  }
  const float tau_use = found ? tau : a;

  // 4. compact candidate indices
  if (t == 0) nlist = 0;
  __syncthreads();
#pragma unroll
  for (int i = 0; i < 32; ++i) {
    if (v[i] >= tau_use) {
      int pos = atomicAdd(&nlist, 1);
      if (pos < 64) list[pos] = (t + (i >> 2) * 256) * 4 + (i & 3);
    }
  }
  __syncthreads();
  const int ncand = nlist < 64 ? nlist : 64;

  // 5. fp64 rescore (wave w handles candidates w, w+4, ...)
  float xr[8];
  {
    const float4* xp = (const float4*)(x + (size_t)r * DD + lane * 8);
    float4 qa = xp[0], qb = xp[1];
    xr[0] = qa.x; xr[1] = qa.y; xr[2] = qa.z; xr[3] = qa.w;
    xr[4] = qb.x; xr[5] = qb.y; xr[6] = qb.z; xr[7] = qb.w;
  }
#pragma unroll 1
  for (int c = w; c < ncand; c += 4) {
    const int ci = list[c];
    const float4* cp = (const float4*)(x + (size_t)ci * DD + lane * 8);
    float4 qa = cp[0], qb = cp[1];
    double s = (double)xr[0] * qa.x + (double)xr[1] * qa.y +
               (double)xr[2] * qa.z + (double)xr[3] * qa.w +
               (double)xr[4] * qb.x + (double)xr[5] * qb.y +
               (double)xr[6] * qb.z + (double)xr[7] * qb.w;
#pragma unroll
    for (int o = 1; o < 64; o <<= 1) s += __shfl_xor(s, o);
    if (lane == 0) dv[c] = s;
  }
  __syncthreads();

  // 6. exact top-16 of candidates (wave 0)
  if (w == 0) {
    double val = (lane < ncand) ? dv[lane] : -1.0e300;
    int myi = (lane < ncand) ? list[lane] : 0;
#pragma unroll 1
    for (int k = 0; k < KTOP; ++k) {
      double mmax = val;
#pragma unroll
      for (int o = 1; o < 64; o <<= 1) mmax = fmax(mmax, __shfl_xor(mmax, o));
      unsigned long long msk = __ballot(val == mmax);
      int wl = (int)__ffsll(msk) - 1;
      if (lane == wl) { fv16[k] = val; fidx16[k] = myi; val = -1.0e300; }
    }
  }
  __syncthreads();

  // 7. zero the row (all loads of rowp long since consumed into regs)
  {
    float4 z; z.x = 0.f; z.y = 0.f; z.z = 0.f; z.w = 0.f;
    float4* rp4 = (float4*)rowp;
#pragma unroll
    for (int i = 0; i < 8; ++i) rp4[t + i * 256] = z;
  }
  __syncthreads();  // vmcnt drained before barrier -> zero-stores ordered

  // 8. scatter
  if (t < KTOP) rowp[fidx16[t]] = (float)fv16[t];
}

extern "C" void kernel_launch(void* const* d_in, const int* in_sizes, int n_in,
                              void* d_out, int out_size, void* d_ws, size_t ws_size,
                              hipStream_t stream) {
  const float* x = (const float*)d_in[0];
  float* out = (float*)d_out;
  float* adj = out + (size_t)NN * DD;

  unsigned short* xb = (unsigned short*)d_ws;  // 8 MiB bf16 copy of x

  knn_cast_copy<<<2048, 256, 0, stream>>>(x, xb, out);
  knn_gemm<<<dim3(64, 64), 256, 0, stream>>>(xb, adj);
  knn_rowtopk<<<NN, 256, 0, stream>>>(x, adj);
}